// Round 11
// baseline (353.511 us; speedup 1.0000x reference)
//
#include <hip/hip_runtime.h>
#include <math.h>

// ---------------- problem constants ----------------
#define NB 16
#define TT 12
#define H1 47
#define W1D 46
#define H2 46
#define W2D 44

typedef short short8v __attribute__((ext_vector_type(8)));
typedef float floatx4 __attribute__((ext_vector_type(4)));

__device__ __forceinline__ short f2bf(float x) {
    unsigned u = __float_as_uint(x);
    u = (u + 0x7FFFu + ((u >> 16) & 1u)) >> 16;   // RNE
    return (short)u;
}
__device__ __forceinline__ float bf2f(short s) {
    return __uint_as_float(((unsigned)(unsigned short)s) << 16);
}
__device__ __forceinline__ float hsig(float z) {
    return fminf(fmaxf(0.2f * z + 0.5f, 0.f), 1.f);
}

// ---------------------------------------------------------------------------
__global__ __launch_bounds__(256) void convert_x(const float* __restrict__ x,
                                                 short* __restrict__ xbf, int n) {
    int i = blockIdx.x * 256 + threadIdx.x;
    if (i < n) xbf[i] = f2bf(x[i]);
}

// Weights -> MFMA B-fragment layout, bf16 (same as R2..R10).
// flat idx = ((c*2+fh)*4+g)*512 + j*32 + ci ; column = g*32+fh*16+j, k = ci
__global__ __launch_bounds__(256) void transform_w(
    const float* __restrict__ W1s, const float* __restrict__ U1s,
    const float* __restrict__ W2s, const float* __restrict__ U2s,
    short* __restrict__ Bt1, short* __restrict__ Bt2)
{
    int idx = blockIdx.x * 256 + threadIdx.x;       // 0..77823
    int layer2 = idx >= 28672;
    int i = layer2 ? idx - 28672 : idx;
    int ci = i & 31, j = (i >> 5) & 15, g = (i >> 9) & 3, fh = (i >> 11) & 1, c = i >> 12;
    int col = g * 32 + fh * 16 + j;
    float v = 0.f;
    if (!layer2) {
        if (c == 0) {
            if (ci < 18) { int kk = ci / 3, cc = ci - kk * 3; v = W1s[(kk * 3 + cc) * 128 + col]; }
        } else {
            v = U1s[((c - 1) * 32 + ci) * 128 + col];
        }
    } else {
        if (c < 6) v = W2s[(c * 32 + ci) * 128 + col];
        else       v = U2s[((c - 6) * 32 + ci) * 128 + col];
    }
    (layer2 ? Bt2 : Bt1)[i] = f2bf(v);
}

// ---------------------------------------------------------------------------
// One ConvLSTM timestep, TWO batches per wave (b0, b0+1).
// Block = 128 thr = 2 waves (fh halves). Tile 4 rows x 16 cols per batch.
// Per k-chunk: 4 B-frag global loads serve 32 MFMAs (2 batches x 4 rows x 4 gates).
// A-operands staged in LDS per batch; cst packed per-thread per batch.
// `first`: recurrent h = 0 and cell = 0 (bit-identical to zeroed buffers).
// ---------------------------------------------------------------------------
template<int LAYER>
__device__ __forceinline__ void step_body(
    const short* __restrict__ xin,     // L1: xbf ; L2: h1 current (bf16)
    const short* __restrict__ hprev,   // recurrent h (bf16)
    const short* __restrict__ Bt,
    const float* __restrict__ bias,
    float* __restrict__ cbase,         // layer cst base (packed)
    short* __restrict__ hnext,
    short* __restrict__ pool, int t2, int t1, int first,
    int b0, int t36, int y0, int x0, short* lds)
{
    constexpr int Ho   = (LAYER == 1) ? H1 : H2;
    constexpr int Wo   = (LAYER == 1) ? W1D : W2D;
    constexpr int NCH  = (LAYER == 1) ? 7 : 12;
    constexpr int REC0 = (LAYER == 1) ? 1 : 6;
    constexpr int IBS  = (LAYER == 1) ? (TT * 48 * 48 * 3) : (H1 * W1D * 32);
    constexpr int HBS  = Ho * Wo * 32;

    const int tid = threadIdx.x;
    const int lane = tid & 63;
    const int fh = tid >> 6;
    const int tx = lane & 15, q = lane >> 4;
    const short8v z8 = (short8v)0;

    short* ldsrec = lds;            // [2][3600]
    short* ldsaux = lds + 7200;     // [2][3600]

    // ---- stage recurrent tiles (both batches): rows y0..y0+4, cols x0-1..x0+16 ----
#pragma unroll
    for (int bb = 0; bb < 2; ++bb) {
        const short* hb0 = hprev + (b0 + bb) * HBS;
        short* dst = ldsrec + bb * 3600;
        for (int i = tid; i < 360; i += 128) {        // 90 pos x 4 chunks(16B)
            int p = i >> 2, c4 = i & 3;
            int row = p / 18, col = p - row * 18;
            int y = y0 + row, x = x0 + col - 1;
            short8v v = z8;
            if (!first && y < Ho && (unsigned)x < (unsigned)Wo)
                v = *(const short8v*)(hb0 + (y * Wo + x) * 32 + c4 * 8);
            *(short8v*)&dst[p * 40 + c4 * 8] = v;
        }
    }

    if (LAYER == 1) {
        // padded im2col of x: m=0..63 (4x16 tile), k=kk*3+cc (18 -> pad 32)
#pragma unroll
        for (int bb = 0; bb < 2; ++bb) {
            const short* xb0 = xin + (b0 + bb) * IBS + t1 * 6912;
            short* dst = ldsaux + bb * 3600;
            for (int i = tid; i < 64 * 32; i += 128) {
                int m = i >> 5, k = i & 31;
                short v = 0;
                if (k < 18) {
                    int kk = k / 3, cc = k - kk * 3;
                    int ky = (kk >= 3) ? 1 : 0, kx = kk - ky * 3;
                    int ys = y0 + (m >> 4) + ky; if (ys > 47) ys = 47;
                    int xs = x0 + (m & 15) + kx; if (xs > 47) xs = 47;
                    v = xb0[(ys * 48 + xs) * 3 + cc];
                }
                dst[m * 40 + k] = v;
            }
        }
    } else {
        // stage input-conv source tiles: rows y0..y0+4 (clamped), cols x0..x0+17
#pragma unroll
        for (int bb = 0; bb < 2; ++bb) {
            const short* ib0 = xin + (b0 + bb) * IBS;
            short* dst = ldsaux + bb * 3600;
            for (int i = tid; i < 360; i += 128) {
                int p = i >> 2, c4 = i & 3;
                int row = p / 18, col = p - row * 18;
                int ys = y0 + row; if (ys > H1 - 1) ys = H1 - 1;
                int xs = x0 + col;
                short8v v = *(const short8v*)(ib0 + (ys * W1D + xs) * 32 + c4 * 8);
                *(short8v*)&dst[p * 40 + c4 * 8] = v;
            }
        }
    }
    __syncthreads();

    const short* Btl = Bt + fh * 2048 + tx * 32 + q * 8;
    floatx4 acc[2][4][4] = {};   // [batch][row][gate]

#pragma unroll
    for (int c = 0; c < NCH; ++c) {
        short8v bf4[4], af[2][4];
#pragma unroll
        for (int g = 0; g < 4; ++g)
            bf4[g] = *(const short8v*)(Btl + c * 4096 + g * 512);

        if (LAYER == 1 && c == 0) {
#pragma unroll
            for (int bb = 0; bb < 2; ++bb)
#pragma unroll
                for (int a = 0; a < 4; ++a)
                    af[bb][a] = *(const short8v*)&ldsaux[bb * 3600 + (a * 16 + tx) * 40 + q * 8];
        } else if (LAYER == 2 && c < REC0) {
            int ky = (c >= 3) ? 1 : 0, kx = c - ky * 3;
#pragma unroll
            for (int bb = 0; bb < 2; ++bb)
#pragma unroll
                for (int a = 0; a < 4; ++a)
                    af[bb][a] = *(const short8v*)&ldsaux[bb * 3600 + ((a + ky) * 18 + tx + kx) * 40 + q * 8];
        } else {
            int kk = c - REC0;
            int ky = (kk >= 3) ? 1 : 0, kx = kk - ky * 3;
#pragma unroll
            for (int bb = 0; bb < 2; ++bb)
#pragma unroll
                for (int a = 0; a < 4; ++a)
                    af[bb][a] = *(const short8v*)&ldsrec[bb * 3600 + ((a + ky) * 18 + tx + kx) * 40 + q * 8];
        }
#pragma unroll
        for (int bb = 0; bb < 2; ++bb)
#pragma unroll
            for (int a = 0; a < 4; ++a)
#pragma unroll
                for (int g = 0; g < 4; ++g)
                    acc[bb][a][g] = __builtin_amdgcn_mfma_f32_16x16x32_bf16(
                        af[bb][a], bf4[g], acc[bb][a][g], 0, 0, 0);
    }

    // ---- fused LSTM epilogue (C layout: M=q*4+r -> x, N=tx(+fh*16) -> f) ----
    const int f = fh * 16 + tx;
    const float bi = bias[f], bfv = bias[32 + f], bcv = bias[64 + f], bov = bias[96 + f];
#pragma unroll
    for (int bb = 0; bb < 2; ++bb) {
        float* cme = cbase + (size_t)((b0 + bb) * 36 + t36) * 2048 + tid * 16;
        float hv[4][4];
#pragma unroll
        for (int a = 0; a < 4; ++a) {
            int y = y0 + a;
            bool yok = y < Ho;
            floatx4 cold;
            if (first) { cold[0] = cold[1] = cold[2] = cold[3] = 0.f; }
            else         cold = *(floatx4*)(cme + a * 4);
            floatx4 cnew;
#pragma unroll
            for (int r = 0; r < 4; ++r) {
                int xe = x0 + q * 4 + r;
                float ig = hsig(acc[bb][a][0][r] + bi);
                float fg = hsig(acc[bb][a][1][r] + bfv);
                float gg = fmaxf(acc[bb][a][2][r] + bcv, 0.f);
                float og = hsig(acc[bb][a][3][r] + bov);
                float cn = fg * cold[r] + ig * gg;
                cnew[r] = cn;
                float hn = 0.f;
                if (yok && xe < Wo) {
                    short hb = f2bf(og * fmaxf(cn, 0.f));
                    hnext[(b0 + bb) * HBS + (y * Wo + xe) * 32 + f] = hb;
                    hn = bf2f(hb);
                }
                hv[a][r] = hn;
            }
            *(floatx4*)(cme + a * 4) = cnew;
        }

        if (LAYER == 2) {
            // MaxPool(2,2): row pairs (0,1),(2,3); col pairs within r
#pragma unroll
            for (int ap = 0; ap < 2; ++ap) {
                int py = y0 / 2 + ap;
#pragma unroll
                for (int rp = 0; rp < 2; ++rp) {
                    int px = x0 / 2 + q * 2 + rp;
                    if (py < 23 && px < 22) {
                        float m = fmaxf(fmaxf(hv[2 * ap][2 * rp],     hv[2 * ap][2 * rp + 1]),
                                        fmaxf(hv[2 * ap + 1][2 * rp], hv[2 * ap + 1][2 * rp + 1]));
                        pool[(size_t)(b0 + bb) * 194304 +
                             ((t2 * 23 + py) * 22 + px) * 32 + f] = f2bf(m);
                    }
                }
            }
        }
    }
}

// ---------------------------------------------------------------------------
// Fused pipeline step. grid = 576 x 128 thr.
// gid: layer = gid&1 ; batch-pair bp = (gid>>1)&7 ; tile = gid>>4 (0..35)
// ---------------------------------------------------------------------------
__global__ __launch_bounds__(128, 2) void fused_step(
    const short* __restrict__ xbf,
    const short* __restrict__ h1r, short* __restrict__ h1w,
    const short* __restrict__ h2r, short* __restrict__ h2w,
    const short* __restrict__ Bt1, const short* __restrict__ Bt2,
    const float* __restrict__ b1, const float* __restrict__ b2,
    float* __restrict__ c1, float* __restrict__ c2,
    short* __restrict__ pool, int t2, int t1,
    int do1, int do2, int first1, int first2)
{
    __shared__ short lds[14400];          // rec [2][3600] + aux [2][3600]
    int gid  = blockIdx.x;
    int layer = gid & 1;
    int b0    = ((gid >> 1) & 7) * 2;
    int t36   = gid >> 4;
    int y0 = (t36 / 3) * 4;
    int x0 = (t36 % 3) * 16;

    if (layer == 0) {
        if (!do1) return;
        step_body<1>(xbf, h1r, Bt1, b1, c1, h1w, nullptr, 0, t1, first1,
                     b0, t36, y0, x0, lds);
    } else {
        if (!do2) return;
        step_body<2>(h1r, h2r, Bt2, b2, c2, h2w, pool, t2, 0, first2,
                     b0, t36, y0, x0, lds);
    }
}

// ---------------------------------------------------------------------------
// gemv: one Wd1 sweep per batch-octet (x2 total). Non-atomic partials:
// d1p[(kc*2+grp)*80 + bb*10 + j], all slots written (no init needed).
// ---------------------------------------------------------------------------
__global__ __launch_bounds__(256) void gemv_kernel(
    const short* __restrict__ p, const float* __restrict__ Wd1, float* __restrict__ d1p)
{
    int grp = blockIdx.y;                // batches grp*8 .. grp*8+7
    int kc = blockIdx.x;                 // 0..63
    int k0 = kc * 3036;                  // 194304 / 64
    float part[8][10];
#pragma unroll
    for (int bb = 0; bb < 8; bb++)
#pragma unroll
        for (int j = 0; j < 10; j++) part[bb][j] = 0.f;

    for (int k = k0 + threadIdx.x; k < k0 + 3036; k += 256) {
        const float* wr = Wd1 + (size_t)k * 10;
        float wv[10];
#pragma unroll
        for (int j = 0; j < 10; j++) wv[j] = wr[j];
#pragma unroll
        for (int bb = 0; bb < 8; bb++) {
            float m = bf2f(p[(size_t)(grp * 8 + bb) * 194304 + k]);
#pragma unroll
            for (int j = 0; j < 10; j++) part[bb][j] = fmaf(m, wv[j], part[bb][j]);
        }
    }
    __shared__ float red[8][10][4];
    int lane = threadIdx.x & 63, wv2 = threadIdx.x >> 6;
#pragma unroll
    for (int bb = 0; bb < 8; bb++)
#pragma unroll
        for (int j = 0; j < 10; j++) {
            float v = part[bb][j];
            for (int off = 32; off > 0; off >>= 1) v += __shfl_down(v, off);
            if (lane == 0) red[bb][j][wv2] = v;
        }
    __syncthreads();
    if (threadIdx.x < 80) {
        int bb = threadIdx.x / 10, j = threadIdx.x % 10;
        d1p[(kc * 2 + grp) * 80 + bb * 10 + j] =
            red[bb][j][0] + red[bb][j][1] + red[bb][j][2] + red[bb][j][3];
    }
}

__global__ void final_dense(const float* __restrict__ d1p, const float* __restrict__ bd1,
                            const float* __restrict__ Wd2, const float* __restrict__ bd2,
                            float* __restrict__ out)
{
    __shared__ float dj[16][10];
    int tid = threadIdx.x;
    if (tid < 160) {
        int b = tid / 10, j = tid % 10, grp = b >> 3, bb = b & 7;
        float s = 0.f;
        for (int kc = 0; kc < 64; kc++)
            s += d1p[(kc * 2 + grp) * 80 + bb * 10 + j];
        dj[b][j] = s + bd1[j];
    }
    __syncthreads();
    if (tid < NB) {
        float s = bd2[0];
#pragma unroll
        for (int j = 0; j < 10; j++) s += dj[tid][j] * Wd2[j];
        out[tid] = s;
    }
}

// ---------------------------------------------------------------------------
extern "C" void kernel_launch(void* const* d_in, const int* in_sizes, int n_in,
                              void* d_out, int out_size, void* d_ws, size_t ws_size,
                              hipStream_t stream)
{
    const float* x   = (const float*)d_in[0];
    const float* W1s = (const float*)d_in[1];
    const float* U1s = (const float*)d_in[2];
    const float* b1  = (const float*)d_in[3];
    const float* W2s = (const float*)d_in[4];
    const float* U2s = (const float*)d_in[5];
    const float* b2  = (const float*)d_in[6];
    const float* Wd1 = (const float*)d_in[7];
    const float* bd1 = (const float*)d_in[8];
    const float* Wd2 = (const float*)d_in[9];
    const float* bd2 = (const float*)d_in[10];
    float* out = (float*)d_out;

    const int H1N = NB * H1 * W1D * 32;   // 1106944
    const int H2N = NB * H2 * W2D * 32;   // 1036288
    const int SLF = 32, SLB = 8192;
    const int SPAN1 = SLF + H1N + SLB;
    const int SPAN2 = SLF + H2N + SLB;
    const int CPL   = 16 * 36 * 2048;     // packed cst floats per layer

    short* Bt1 = (short*)d_ws;            // 28672
    short* Bt2 = Bt1 + 28672;             // 49152
    short* xbf = Bt2 + 49152;             // 1327104
    short* p   = xbf + 1327104;           // 3108864
    short* hr  = p + 3108864;
    short* h1a = hr + SLF;
    short* h1b = hr + SPAN1 + SLF;
    short* h2a = hr + 2 * SPAN1 + SLF;
    short* h2b = hr + 2 * SPAN1 + SPAN2 + SLF;
    float* c1  = (float*)(hr + 2 * SPAN1 + 2 * SPAN2);
    float* c2  = c1 + CPL;
    float* d1p = c2 + CPL;                // 10240 floats

    convert_x<<<(1327104 + 255) / 256, 256, 0, stream>>>(x, xbf, 1327104);
    transform_w<<<304, 256, 0, stream>>>(W1s, U1s, W2s, U2s, Bt1, Bt2);

    // software pipeline: kernel s runs L1(t=s) and L2(t=s-1)
    for (int s = 0; s <= TT; s++) {
        short*       h1w = (s & 1) ? h1b : h1a;
        const short* h1r = (s & 1) ? h1a : h1b;
        short*       h2w = (s & 1) ? h2a : h2b;
        const short* h2r = (s & 1) ? h2b : h2a;
        fused_step<<<dim3(576), 128, 0, stream>>>(
            xbf, h1r, h1w, h2r, h2w, Bt1, Bt2, b1, b2, c1, c2,
            p, s - 1, (s < TT ? s : 0),
            (int)(s < TT), (int)(s >= 1), (int)(s == 0), (int)(s == 1));
    }

    gemv_kernel<<<dim3(64, 2), 256, 0, stream>>>(p, Wd1, d1p);
    final_dense<<<1, 192, 0, stream>>>(d1p, bd1, Wd2, bd2, out);
}

// Round 12
// 311.976 us; speedup vs baseline: 1.1331x; 1.1331x over previous
//
#include <hip/hip_runtime.h>
#include <math.h>

// ---------------- problem constants ----------------
#define NB 16
#define TT 12
#define H1 47
#define W1D 46
#define H2 46
#define W2D 44

typedef short short8v __attribute__((ext_vector_type(8)));
typedef float floatx4 __attribute__((ext_vector_type(4)));

__device__ __forceinline__ short f2bf(float x) {
    unsigned u = __float_as_uint(x);
    u = (u + 0x7FFFu + ((u >> 16) & 1u)) >> 16;   // RNE
    return (short)u;
}
__device__ __forceinline__ float bf2f(short s) {
    return __uint_as_float(((unsigned)(unsigned short)s) << 16);
}
__device__ __forceinline__ float hsig(float z) {
    return fminf(fmaxf(0.2f * z + 0.5f, 0.f), 1.f);
}

// ---------------------------------------------------------------------------
__global__ __launch_bounds__(256) void convert_x(const float* __restrict__ x,
                                                 short* __restrict__ xbf, int n) {
    int i = blockIdx.x * 256 + threadIdx.x;
    if (i < n) xbf[i] = f2bf(x[i]);
}

// Weights -> MFMA B-fragment layout, bf16 (same as R2..R10).
// flat idx = ((c*2+fh)*4+g)*512 + j*32 + ci ; column = g*32+fh*16+j, k = ci
__global__ __launch_bounds__(256) void transform_w(
    const float* __restrict__ W1s, const float* __restrict__ U1s,
    const float* __restrict__ W2s, const float* __restrict__ U2s,
    short* __restrict__ Bt1, short* __restrict__ Bt2)
{
    int idx = blockIdx.x * 256 + threadIdx.x;       // 0..77823
    int layer2 = idx >= 28672;
    int i = layer2 ? idx - 28672 : idx;
    int ci = i & 31, j = (i >> 5) & 15, g = (i >> 9) & 3, fh = (i >> 11) & 1, c = i >> 12;
    int col = g * 32 + fh * 16 + j;
    float v = 0.f;
    if (!layer2) {
        if (c == 0) {
            if (ci < 18) { int kk = ci / 3, cc = ci - kk * 3; v = W1s[(kk * 3 + cc) * 128 + col]; }
        } else {
            v = U1s[((c - 1) * 32 + ci) * 128 + col];
        }
    } else {
        if (c < 6) v = W2s[(c * 32 + ci) * 128 + col];
        else       v = U2s[((c - 6) * 32 + ci) * 128 + col];
    }
    (layer2 ? Bt2 : Bt1)[i] = f2bf(v);
}

// ---------------------------------------------------------------------------
// One ConvLSTM timestep body (R7 structure, proven 301us).
// Block = 128 thr = 2 waves (fh halves). Tile 4 rows x 16 cols.
// A-operands staged in LDS (zeros baked in); K-loop VMEM = B-frags only.
// cst packed per-thread. `first`: recurrent h = 0 and cell = 0 (cold start,
// bit-identical to reading a zeroed buffer).
// ---------------------------------------------------------------------------
template<int LAYER>
__device__ __forceinline__ void step_body(
    const short* __restrict__ xin,     // L1: xbf ; L2: h1 current (bf16)
    const short* __restrict__ hprev,   // recurrent h (bf16)
    const short* __restrict__ Bt,
    const float* __restrict__ bias,
    float* __restrict__ cstp,          // packed: + tid*16 + a*4 + r
    short* __restrict__ hnext,
    short* __restrict__ pool, int t2, int t1, int first,
    int b, int y0, int x0, short* ldsrec, short* ldsaux)
{
    constexpr int Ho   = (LAYER == 1) ? H1 : H2;
    constexpr int Wo   = (LAYER == 1) ? W1D : W2D;
    constexpr int NCH  = (LAYER == 1) ? 7 : 12;
    constexpr int REC0 = (LAYER == 1) ? 1 : 6;
    constexpr int IBS  = (LAYER == 1) ? (TT * 48 * 48 * 3) : (H1 * W1D * 32);
    constexpr int HBS  = Ho * Wo * 32;

    const int tid = threadIdx.x;
    const int lane = tid & 63;
    const int fh = tid >> 6;
    const int tx = lane & 15, q = lane >> 4;
    const short8v z8 = (short8v)0;

    // ---- stage recurrent tile: rows y0..y0+4, cols x0-1..x0+16, SAME-pad zeros ----
    {
        const short* hb0 = hprev + b * HBS;
        for (int i = tid; i < 360; i += 128) {        // 90 pos x 4 chunks(16B)
            int p = i >> 2, c4 = i & 3;
            int row = p / 18, col = p - row * 18;
            int y = y0 + row, x = x0 + col - 1;
            short8v v = z8;
            if (!first && y < Ho && (unsigned)x < (unsigned)Wo)
                v = *(const short8v*)(hb0 + (y * Wo + x) * 32 + c4 * 8);
            *(short8v*)&ldsrec[p * 40 + c4 * 8] = v;
        }
    }

    if (LAYER == 1) {
        // padded im2col of x: m=0..63 (4x16 tile), k=kk*3+cc (18 -> pad 32)
        const short* xb0 = xin + b * IBS + t1 * 6912;
        for (int i = tid; i < 64 * 32; i += 128) {
            int m = i >> 5, k = i & 31;
            short v = 0;
            if (k < 18) {
                int kk = k / 3, cc = k - kk * 3;
                int ky = (kk >= 3) ? 1 : 0, kx = kk - ky * 3;
                int ys = y0 + (m >> 4) + ky; if (ys > 47) ys = 47;
                int xs = x0 + (m & 15) + kx; if (xs > 47) xs = 47;
                v = xb0[(ys * 48 + xs) * 3 + cc];
            }
            ldsaux[m * 40 + k] = v;
        }
    } else {
        // stage input-conv source tile: rows y0..y0+4 (clamped), cols x0..x0+17
        // (OOB cols land in slack; garbage feeds only masked outputs)
        const short* ib0 = xin + b * IBS;
        for (int i = tid; i < 360; i += 128) {
            int p = i >> 2, c4 = i & 3;
            int row = p / 18, col = p - row * 18;
            int ys = y0 + row; if (ys > H1 - 1) ys = H1 - 1;
            int xs = x0 + col;
            short8v v = *(const short8v*)(ib0 + (ys * W1D + xs) * 32 + c4 * 8);
            *(short8v*)&ldsaux[p * 40 + c4 * 8] = v;
        }
    }
    __syncthreads();

    const short* Btl = Bt + fh * 2048 + tx * 32 + q * 8;
    floatx4 acc[4][4] = {};   // [a(row)][gate]

#pragma unroll
    for (int c = 0; c < NCH; ++c) {
        short8v bf4[4], af[4];
#pragma unroll
        for (int g = 0; g < 4; ++g)
            bf4[g] = *(const short8v*)(Btl + c * 4096 + g * 512);

        if (LAYER == 1 && c == 0) {
#pragma unroll
            for (int a = 0; a < 4; ++a)
                af[a] = *(const short8v*)&ldsaux[(a * 16 + tx) * 40 + q * 8];
        } else if (LAYER == 2 && c < REC0) {
            int ky = (c >= 3) ? 1 : 0, kx = c - ky * 3;
#pragma unroll
            for (int a = 0; a < 4; ++a)
                af[a] = *(const short8v*)&ldsaux[(((a + ky) * 18 + tx + kx)) * 40 + q * 8];
        } else {
            int kk = c - REC0;
            int ky = (kk >= 3) ? 1 : 0, kx = kk - ky * 3;
#pragma unroll
            for (int a = 0; a < 4; ++a)
                af[a] = *(const short8v*)&ldsrec[(((a + ky) * 18 + tx + kx)) * 40 + q * 8];
        }
#pragma unroll
        for (int a = 0; a < 4; ++a)
#pragma unroll
            for (int g = 0; g < 4; ++g)
                acc[a][g] = __builtin_amdgcn_mfma_f32_16x16x32_bf16(af[a], bf4[g], acc[a][g], 0, 0, 0);
    }

    // ---- fused LSTM epilogue (C layout: M=q*4+r -> x, N=tx(+fh*16) -> f) ----
    const int f = fh * 16 + tx;
    const float bi = bias[f], bfv = bias[32 + f], bcv = bias[64 + f], bov = bias[96 + f];
    float* cme = cstp + tid * 16;
    float hv[4][4];
#pragma unroll
    for (int a = 0; a < 4; ++a) {
        int y = y0 + a;
        bool yok = y < Ho;
        floatx4 cold;
        if (first) { cold[0] = cold[1] = cold[2] = cold[3] = 0.f; }
        else         cold = *(floatx4*)(cme + a * 4);
        floatx4 cnew;
#pragma unroll
        for (int r = 0; r < 4; ++r) {
            int xe = x0 + q * 4 + r;
            float ig = hsig(acc[a][0][r] + bi);
            float fg = hsig(acc[a][1][r] + bfv);
            float gg = fmaxf(acc[a][2][r] + bcv, 0.f);
            float og = hsig(acc[a][3][r] + bov);
            float cn = fg * cold[r] + ig * gg;
            cnew[r] = cn;
            float hn = 0.f;
            if (yok && xe < Wo) {
                short hb = f2bf(og * fmaxf(cn, 0.f));
                hnext[b * HBS + (y * Wo + xe) * 32 + f] = hb;
                hn = bf2f(hb);
            }
            hv[a][r] = hn;
        }
        *(floatx4*)(cme + a * 4) = cnew;
    }

    if (LAYER == 2) {
        // MaxPool(2,2): row pairs (0,1),(2,3); col pairs within r
#pragma unroll
        for (int ap = 0; ap < 2; ++ap) {
            int py = y0 / 2 + ap;
#pragma unroll
            for (int rp = 0; rp < 2; ++rp) {
                int px = x0 / 2 + q * 2 + rp;
                if (py < 23 && px < 22) {
                    float m = fmaxf(fmaxf(hv[2 * ap][2 * rp],     hv[2 * ap][2 * rp + 1]),
                                    fmaxf(hv[2 * ap + 1][2 * rp], hv[2 * ap + 1][2 * rp + 1]));
                    pool[(size_t)b * 194304 + ((t2 * 23 + py) * 22 + px) * 32 + f] = f2bf(m);
                }
            }
        }
    }
}

// ---------------------------------------------------------------------------
// Fused pipeline step. grid = 1152 x 128 thr.
// gid: layer = gid&1 ; b = (gid>>1)&15 ; tile = gid>>5 (0..35)
// NOTE: no min-waves arg — R10's (128,3) cap regressed (suspected spills).
// ---------------------------------------------------------------------------
__global__ __launch_bounds__(128) void fused_step(
    const short* __restrict__ xbf,
    const short* __restrict__ h1r, short* __restrict__ h1w,
    const short* __restrict__ h2r, short* __restrict__ h2w,
    const short* __restrict__ Bt1, const short* __restrict__ Bt2,
    const float* __restrict__ b1, const float* __restrict__ b2,
    float* __restrict__ c1, float* __restrict__ c2,
    short* __restrict__ pool, int t2, int t1,
    int do1, int do2, int first1, int first2)
{
    __shared__ short lds[7200];           // rec [3600] + aux [3600]
    int gid  = blockIdx.x;
    int layer = gid & 1;
    int b     = (gid >> 1) & 15;
    int t36   = gid >> 5;
    int y0 = (t36 / 3) * 4;
    int x0 = (t36 % 3) * 16;

    if (layer == 0) {
        if (!do1) return;
        float* cstp = c1 + (size_t)(b * 36 + t36) * 2048;
        step_body<1>(xbf, h1r, Bt1, b1, cstp, h1w, nullptr, 0, t1, first1,
                     b, y0, x0, lds, lds + 3600);
    } else {
        if (!do2) return;
        float* cstp = c2 + (size_t)(b * 36 + t36) * 2048;
        step_body<2>(h1r, h2r, Bt2, b2, cstp, h2w, pool, t2, 0, first2,
                     b, y0, x0, lds, lds + 3600);
    }
}

// ---------------------------------------------------------------------------
// gemv: one Wd1 sweep per batch-octet (x2 total). Non-atomic partials:
// d1p[(kc*2+grp)*80 + bb*10 + j], all slots written (no init needed).
// ---------------------------------------------------------------------------
__global__ __launch_bounds__(256) void gemv_kernel(
    const short* __restrict__ p, const float* __restrict__ Wd1, float* __restrict__ d1p)
{
    int grp = blockIdx.y;                // batches grp*8 .. grp*8+7
    int kc = blockIdx.x;                 // 0..63
    int k0 = kc * 3036;                  // 194304 / 64
    float part[8][10];
#pragma unroll
    for (int bb = 0; bb < 8; bb++)
#pragma unroll
        for (int j = 0; j < 10; j++) part[bb][j] = 0.f;

    for (int k = k0 + threadIdx.x; k < k0 + 3036; k += 256) {
        const float* wr = Wd1 + (size_t)k * 10;
        float wv[10];
#pragma unroll
        for (int j = 0; j < 10; j++) wv[j] = wr[j];
#pragma unroll
        for (int bb = 0; bb < 8; bb++) {
            float m = bf2f(p[(size_t)(grp * 8 + bb) * 194304 + k]);
#pragma unroll
            for (int j = 0; j < 10; j++) part[bb][j] = fmaf(m, wv[j], part[bb][j]);
        }
    }
    __shared__ float red[8][10][4];
    int lane = threadIdx.x & 63, wv2 = threadIdx.x >> 6;
#pragma unroll
    for (int bb = 0; bb < 8; bb++)
#pragma unroll
        for (int j = 0; j < 10; j++) {
            float v = part[bb][j];
            for (int off = 32; off > 0; off >>= 1) v += __shfl_down(v, off);
            if (lane == 0) red[bb][j][wv2] = v;
        }
    __syncthreads();
    if (threadIdx.x < 80) {
        int bb = threadIdx.x / 10, j = threadIdx.x % 10;
        d1p[(kc * 2 + grp) * 80 + bb * 10 + j] =
            red[bb][j][0] + red[bb][j][1] + red[bb][j][2] + red[bb][j][3];
    }
}

__global__ void final_dense(const float* __restrict__ d1p, const float* __restrict__ bd1,
                            const float* __restrict__ Wd2, const float* __restrict__ bd2,
                            float* __restrict__ out)
{
    __shared__ float dj[16][10];
    int tid = threadIdx.x;
    if (tid < 160) {
        int b = tid / 10, j = tid % 10, grp = b >> 3, bb = b & 7;
        float s = 0.f;
        for (int kc = 0; kc < 64; kc++)
            s += d1p[(kc * 2 + grp) * 80 + bb * 10 + j];
        dj[b][j] = s + bd1[j];
    }
    __syncthreads();
    if (tid < NB) {
        float s = bd2[0];
#pragma unroll
        for (int j = 0; j < 10; j++) s += dj[tid][j] * Wd2[j];
        out[tid] = s;
    }
}

// ---------------------------------------------------------------------------
extern "C" void kernel_launch(void* const* d_in, const int* in_sizes, int n_in,
                              void* d_out, int out_size, void* d_ws, size_t ws_size,
                              hipStream_t stream)
{
    const float* x   = (const float*)d_in[0];
    const float* W1s = (const float*)d_in[1];
    const float* U1s = (const float*)d_in[2];
    const float* b1  = (const float*)d_in[3];
    const float* W2s = (const float*)d_in[4];
    const float* U2s = (const float*)d_in[5];
    const float* b2  = (const float*)d_in[6];
    const float* Wd1 = (const float*)d_in[7];
    const float* bd1 = (const float*)d_in[8];
    const float* Wd2 = (const float*)d_in[9];
    const float* bd2 = (const float*)d_in[10];
    float* out = (float*)d_out;

    const int H1N = NB * H1 * W1D * 32;   // 1106944
    const int H2N = NB * H2 * W2D * 32;   // 1036288
    const int SLF = 32, SLB = 8192;
    const int SPAN1 = SLF + H1N + SLB;
    const int SPAN2 = SLF + H2N + SLB;
    const int CPL   = 16 * 36 * 2048;     // packed cst floats per layer

    short* Bt1 = (short*)d_ws;            // 28672
    short* Bt2 = Bt1 + 28672;             // 49152
    short* xbf = Bt2 + 49152;             // 1327104
    short* p   = xbf + 1327104;           // 3108864
    short* hr  = p + 3108864;
    short* h1a = hr + SLF;
    short* h1b = hr + SPAN1 + SLF;
    short* h2a = hr + 2 * SPAN1 + SLF;
    short* h2b = hr + 2 * SPAN1 + SPAN2 + SLF;
    float* c1  = (float*)(hr + 2 * SPAN1 + 2 * SPAN2);
    float* c2  = c1 + CPL;
    float* d1p = c2 + CPL;                // 10240 floats

    convert_x<<<(1327104 + 255) / 256, 256, 0, stream>>>(x, xbf, 1327104);
    transform_w<<<304, 256, 0, stream>>>(W1s, U1s, W2s, U2s, Bt1, Bt2);

    // software pipeline: kernel s runs L1(t=s) and L2(t=s-1)
    for (int s = 0; s <= TT; s++) {
        short*       h1w = (s & 1) ? h1b : h1a;
        const short* h1r = (s & 1) ? h1a : h1b;
        short*       h2w = (s & 1) ? h2a : h2b;
        const short* h2r = (s & 1) ? h2b : h2a;
        fused_step<<<dim3(1152), 128, 0, stream>>>(
            xbf, h1r, h1w, h2r, h2w, Bt1, Bt2, b1, b2, c1, c2,
            p, s - 1, (s < TT ? s : 0),
            (int)(s < TT), (int)(s >= 1), (int)(s == 0), (int)(s == 1));
    }

    gemv_kernel<<<dim3(64, 2), 256, 0, stream>>>(p, Wd1, d1p);
    final_dense<<<1, 192, 0, stream>>>(d1p, bd1, Wd2, bd2, out);
}